// Round 6
// baseline (129.446 us; speedup 1.0000x reference)
//
#include <hip/hip_runtime.h>
#include <math.h>

// SP_loss: s = X X^T / T (N=8192, D=256, T=0.04, groups of 4).
// loss = mean_g softplus((neg[g] - margin[g]) / T)
//   neg[g]    = T * log sum_{i in g, j not in g} exp(s[i,j])
//               -> MX-fp8 (e4m3, K=128 scaled MFMA) symmetric GEMM over
//                  upper-tri 64x64 tiles, ONE WAVE PER BLOCK, no LDS, no
//                  barriers: fragments loaded directly from global (L2-hit),
//                  fused exp + group-sum via 32 atomics/wave.
//   margin[g] = exact fp32 4x4 group Gram block (hard_pos / least_pos / alpha)
//
// Why 1-wave blocks: R2 (bf16, 16 barriers) and R5 (fp8, 3 barriers) both
// landed at ~48 us despite ~10 us of issue work -> 4-wave blocks stall in a
// barrier convoy (co-resident blocks stage/drain in lockstep). Waves here are
// fully independent; ~12/CU co-resident hide all memory latency.
// No device-scope fences (R3/R4: threadfence => buffer_wbl2 => ~180 us).
//
// X pre-scaled by 16 into fp8; E8M0 scales 2^-4 per operand undo it exactly
// in HW (verified R4/R5: absmax 0.0; same per-lane fragment pattern).

#define NROWS 8192
#define DDIM  256
#define NGRP  2048
#define NTB   128                       // 8192 / 64 tiles per dim
#define NTILES (NTB * (NTB + 1) / 2)    // 8256
#define T_CONST 0.04f
#define INV_T   25.0f
#define EXP2_SCALE 36.06737602222409f   // 25 * log2(e)
#define SCALE_QTR 0x7B7B7B7Bu           // E8M0 123 = 2^-4 in every byte

typedef __attribute__((ext_vector_type(8))) int   i32x8_t;
typedef __attribute__((ext_vector_type(4))) int   i32x4_t;
typedef __attribute__((ext_vector_type(4))) float f32x4_t;

// Kernel A (fused prep): blocks 0..2047 convert fp32 -> fp8 e4m3 (x*16, RNE) +
// zero grpsum; blocks 2048..2559 compute margin[g] (4 groups/block, 1 wave each).
__global__ __launch_bounds__(256) void prep_kernel(const float* __restrict__ x,
                                                   unsigned int* __restrict__ xq,
                                                   float* __restrict__ grpsum,
                                                   float* __restrict__ margin) {
    const int b = blockIdx.x;
    if (b < 2048) {
        int gid = b * 256 + threadIdx.x;
        float4 v = *(const float4*)(x + gid * 4);
        int pk = __builtin_amdgcn_cvt_pk_fp8_f32(v.x * 16.f, v.y * 16.f, 0, false);
        pk = __builtin_amdgcn_cvt_pk_fp8_f32(v.z * 16.f, v.w * 16.f, pk, true);
        xq[gid] = (unsigned int)pk;
        if (gid < NGRP) grpsum[gid] = 0.f;
        return;
    }
    const int g = (b - 2048) * 4 + (threadIdx.x >> 6);
    const int lane = threadIdx.x & 63;
    const float* xr = x + (size_t)g * 4 * DDIM;
    float a[16];
#pragma unroll
    for (int k = 0; k < 16; ++k) a[k] = 0.f;
    for (int e = lane; e < DDIM; e += 64) {
        float vv[4];
        vv[0] = xr[e];
        vv[1] = xr[DDIM + e];
        vv[2] = xr[2 * DDIM + e];
        vv[3] = xr[3 * DDIM + e];
#pragma unroll
        for (int i = 0; i < 4; ++i)
#pragma unroll
            for (int j = 0; j < 4; ++j)
                a[i * 4 + j] = fmaf(vv[i], vv[j], a[i * 4 + j]);
    }
#pragma unroll
    for (int k = 0; k < 16; ++k) {
        float t = a[k];
        t += __shfl_xor(t, 32, 64);
        t += __shfl_xor(t, 16, 64);
        t += __shfl_xor(t, 8, 64);
        t += __shfl_xor(t, 4, 64);
        t += __shfl_xor(t, 2, 64);
        t += __shfl_xor(t, 1, 64);
        a[k] = t;
    }
    if (lane == 0) {
        float pos[16];
#pragma unroll
        for (int k = 0; k < 16; ++k) pos[k] = a[k] * INV_T;

        float mx = -pos[0];
#pragma unroll
        for (int k = 1; k < 16; ++k) mx = fmaxf(mx, -pos[k]);
        float se = 0.f;
#pragma unroll
        for (int k = 0; k < 16; ++k) se += __expf(-pos[k] - mx);
        float hard_pos = -T_CONST * (mx + __logf(se));

        float lse_row[4];
#pragma unroll
        for (int i = 0; i < 4; ++i) {
            float m2 = -pos[i * 4];
#pragma unroll
            for (int j = 1; j < 4; ++j) m2 = fmaxf(m2, -pos[i * 4 + j]);
            float s2 = 0.f;
#pragma unroll
            for (int j = 0; j < 4; ++j) s2 += __expf(-pos[i * 4 + j] - m2);
            lse_row[i] = m2 + __logf(s2);
        }
        float m3 = -lse_row[0];
#pragma unroll
        for (int i = 1; i < 4; ++i) m3 = fmaxf(m3, -lse_row[i]);
        float s3 = 0.f;
#pragma unroll
        for (int i = 0; i < 4; ++i) s3 += __expf(-lse_row[i] - m3);
        float least_pos = T_CONST * (m3 + __logf(s3));

        float alpha = (hard_pos >= 0.f)
                          ? (2.f * least_pos * hard_pos) / (hard_pos + least_pos)
                          : 0.f;
        margin[g] = alpha * hard_pos + (1.f - alpha) * least_pos;
    }
}

// Kernel B: one wave per upper-tri 64x64 tile (8256 blocks of 64 threads).
// Direct global fragment loads (same per-lane layout as the LDS version that
// verified bit-exact: lane(l16,quad) of mi reads row mi*16+l16, bytes
// ks*128 + quad*32 .. +31). No LDS, no barriers. acc C/D layout:
// col = ni*16 + l16, row = mi*16 + quad*4 + reg  -> reg spans ONE group.
__global__ __launch_bounds__(64, 3) void gemm_exp_grpsum(const unsigned char* __restrict__ xq,
                                                         float* __restrict__ grpsum) {
    // decode upper-triangular (ti, tj), ti <= tj: off(ti) = ti*(257-ti)/2
    const int idx = blockIdx.x;
    int ti = (int)((257.0f - sqrtf(66049.0f - 8.0f * (float)idx)) * 0.5f);
    while (ti * (257 - ti) / 2 > idx) --ti;
    while ((ti + 1) * (256 - ti) / 2 <= idx) ++ti;
    const int tj = ti + (idx - ti * (257 - ti) / 2);
    const int row0 = ti * 64;
    const int col0 = tj * 64;
    const bool diag = (ti == tj);

    const int lane = threadIdx.x;
    const int quad = lane >> 4;
    const int l16 = lane & 15;

    f32x4_t acc[4][4];
#pragma unroll
    for (int i = 0; i < 4; ++i)
#pragma unroll
        for (int j = 0; j < 4; ++j)
            acc[i][j] = (f32x4_t){0.f, 0.f, 0.f, 0.f};

#pragma unroll
    for (int ks = 0; ks < 2; ++ks) {
        i32x8_t aF[4], bF[4];
#pragma unroll
        for (int mi = 0; mi < 4; ++mi) {
            const unsigned char* pa =
                xq + ((size_t)(row0 + mi * 16 + l16) << 8) + ks * 128 + quad * 32;
            i32x4_t lo = *(const i32x4_t*)pa;
            i32x4_t hi = *(const i32x4_t*)(pa + 16);
            aF[mi] = __builtin_shufflevector(lo, hi, 0, 1, 2, 3, 4, 5, 6, 7);
        }
#pragma unroll
        for (int ni = 0; ni < 4; ++ni) {
            const unsigned char* pb =
                xq + ((size_t)(col0 + ni * 16 + l16) << 8) + ks * 128 + quad * 32;
            i32x4_t lo = *(const i32x4_t*)pb;
            i32x4_t hi = *(const i32x4_t*)(pb + 16);
            bF[ni] = __builtin_shufflevector(lo, hi, 0, 1, 2, 3, 4, 5, 6, 7);
        }
#pragma unroll
        for (int mi = 0; mi < 4; ++mi)
#pragma unroll
            for (int ni = 0; ni < 4; ++ni)
                acc[mi][ni] = __builtin_amdgcn_mfma_scale_f32_16x16x128_f8f6f4(
                    aF[mi], bF[ni], acc[mi][ni],
                    0, 0,                       // fp8 e4m3 A and B
                    0, (int)SCALE_QTR,          // scale A = 2^-4
                    0, (int)SCALE_QTR);         // scale B = 2^-4
    }

    // ---- epilogue: exp + group-granularity sums ----
    // row-group of (mi,quad) = row0/4 + mi*4 + quad  (reg spans the group)
    // col-group of (ni,l16)  = col0/4 + ni*4 + (l16>>2)
    const int rg0 = row0 >> 2;
    const int cg0 = col0 >> 2;
    float rowg[4] = {0.f, 0.f, 0.f, 0.f};   // per mi
    float colp[4] = {0.f, 0.f, 0.f, 0.f};   // per ni (per-lane col partial)

    if (!diag) {
#pragma unroll
        for (int mi = 0; mi < 4; ++mi)
#pragma unroll
            for (int reg = 0; reg < 4; ++reg)
#pragma unroll
                for (int ni = 0; ni < 4; ++ni) {
                    float e = exp2f(acc[mi][ni][reg] * EXP2_SCALE);
                    rowg[mi] += e;
                    colp[ni] += e;
                }
    } else {
#pragma unroll
        for (int mi = 0; mi < 4; ++mi) {
            const int rgrp = mi * 4 + quad;          // group within tile
#pragma unroll
            for (int reg = 0; reg < 4; ++reg)
#pragma unroll
                for (int ni = 0; ni < 4; ++ni) {
                    const int cgrp = ni * 4 + (l16 >> 2);
                    float e = (cgrp == rgrp) ? 0.f
                                             : exp2f(acc[mi][ni][reg] * EXP2_SCALE);
                    rowg[mi] += e;
                }
        }
    }

    // row groups: reduce over the 16 col-lanes within each quad-phase.
#pragma unroll
    for (int mi = 0; mi < 4; ++mi) {
        float v = rowg[mi];
        v += __shfl_xor(v, 1, 64);
        v += __shfl_xor(v, 2, 64);
        v += __shfl_xor(v, 4, 64);
        v += __shfl_xor(v, 8, 64);
        if (l16 == 0) atomicAdd(&grpsum[rg0 + mi * 4 + quad], v);
    }
    if (!diag) {
        // col groups: reduce over quad (xor 16,32) and within 4-lane cluster (xor 1,2).
#pragma unroll
        for (int ni = 0; ni < 4; ++ni) {
            float v = colp[ni];
            v += __shfl_xor(v, 16, 64);
            v += __shfl_xor(v, 32, 64);
            v += __shfl_xor(v, 1, 64);
            v += __shfl_xor(v, 2, 64);
            if (quad == 0 && (l16 & 3) == 0)
                atomicAdd(&grpsum[cg0 + ni * 4 + (l16 >> 2)], v);
        }
    }
}

// Kernel C: neg[g] = T*log(grpsum[g]); loss = mean softplus((neg-margin)/T).
__global__ __launch_bounds__(256) void finalize_kernel(const float* __restrict__ grpsum,
                                                       const float* __restrict__ margin,
                                                       float* __restrict__ out) {
    const int tid = threadIdx.x;
    float local = 0.f;
    for (int g = tid; g < NGRP; g += 256) {
        float z = __logf(grpsum[g]) - margin[g] * INV_T;   // (neg - margin)/T
        float sp = (z > 30.f) ? z : log1pf(__expf(z));
        local += sp;
    }
    local += __shfl_xor(local, 1, 64);
    local += __shfl_xor(local, 2, 64);
    local += __shfl_xor(local, 4, 64);
    local += __shfl_xor(local, 8, 64);
    local += __shfl_xor(local, 16, 64);
    local += __shfl_xor(local, 32, 64);
    __shared__ float wsum[4];
    if ((tid & 63) == 0) wsum[tid >> 6] = local;
    __syncthreads();
    if (tid == 0) out[0] = (wsum[0] + wsum[1] + wsum[2] + wsum[3]) * (1.f / (float)NGRP);
}

extern "C" void kernel_launch(void* const* d_in, const int* in_sizes, int n_in,
                              void* d_out, int out_size, void* d_ws, size_t ws_size,
                              hipStream_t stream) {
    const float* x = (const float*)d_in[0];
    float* out = (float*)d_out;

    unsigned int* xq = (unsigned int*)d_ws;                                  // 2 MiB fp8 X*16
    float* grpsum = (float*)((char*)d_ws + (size_t)NROWS * DDIM);            // 8 KiB
    float* margin = grpsum + NGRP;                                           // 8 KiB

    prep_kernel<<<2048 + 512, 256, 0, stream>>>(x, xq, grpsum, margin);
    gemm_exp_grpsum<<<NTILES, 64, 0, stream>>>((const unsigned char*)xq, grpsum);
    finalize_kernel<<<1, 256, 0, stream>>>(grpsum, margin, out);
}

// Round 7
// 116.634 us; speedup vs baseline: 1.1098x; 1.1098x over previous
//
#include <hip/hip_runtime.h>
#include <math.h>

// SP_loss: s = X X^T / T (N=8192, D=256, T=0.04, groups of 4).
// loss = mean_g softplus((neg[g] - margin[g]) / T)
//   neg[g]    = T * log sum_{i in g, j not in g} exp(s[i,j])
//               -> MX-fp8 (e4m3, K=128 scaled MFMA) symmetric GEMM over
//                  upper-tri 64x64 tiles, 1 wave per WG, NO LDS/barriers,
//                  TPW=4 tiles per wave (A-fragments register-resident),
//                  fused exp + group-sum atomics.
//   margin[g] = exact fp32 4x4 group Gram block (hard_pos / least_pos / alpha)
//
// R6 post-mortem: 8256 one-wave WGs stalled ~30K cyc/wave with every pipe idle
// -> suspected per-WG create/drain churn. This round: identical tile math
// (verified absmax 0.0) but 4 tiles per wave = 2064 WGs, A loaded once.
// No device-scope fences (R3/R4: threadfence => buffer_wbl2 => ~180 us).

#define NROWS 8192
#define DDIM  256
#define NGRP  2048
#define NTB   128                       // 8192 / 64 tiles per dim
#define NTILES (NTB * (NTB + 1) / 2)    // 8256
#define TPW   4                         // tiles per wave
#define NWG   (NTILES / TPW)            // 2064
#define T_CONST 0.04f
#define INV_T   25.0f
#define EXP2_SCALE 36.06737602222409f   // 25 * log2(e)
#define SCALE_QTR 0x7B7B7B7Bu           // E8M0 123 = 2^-4 in every byte

typedef __attribute__((ext_vector_type(8))) int   i32x8_t;
typedef __attribute__((ext_vector_type(4))) int   i32x4_t;
typedef __attribute__((ext_vector_type(4))) float f32x4_t;

// Kernel A (fused prep): blocks 0..511 convert fp32 -> fp8 e4m3 (x*16, RNE,
// grid-stride x4) + zero grpsum; blocks 512..1023 compute margin[g]
// (4 groups/block, 1 wave each). 1024 WGs total (was 2560).
__global__ __launch_bounds__(256) void prep_kernel(const float* __restrict__ x,
                                                   unsigned int* __restrict__ xq,
                                                   float* __restrict__ grpsum,
                                                   float* __restrict__ margin) {
    const int b = blockIdx.x;
    if (b < 512) {
#pragma unroll
        for (int it = 0; it < 4; ++it) {
            int gid = it * 131072 + b * 256 + threadIdx.x;
            float4 v = *(const float4*)(x + (size_t)gid * 4);
            int pk = __builtin_amdgcn_cvt_pk_fp8_f32(v.x * 16.f, v.y * 16.f, 0, false);
            pk = __builtin_amdgcn_cvt_pk_fp8_f32(v.z * 16.f, v.w * 16.f, pk, true);
            xq[gid] = (unsigned int)pk;
            if (it == 0 && gid < NGRP) grpsum[gid] = 0.f;
        }
        return;
    }
    const int g = (b - 512) * 4 + (threadIdx.x >> 6);
    const int lane = threadIdx.x & 63;
    const float* xr = x + (size_t)g * 4 * DDIM;
    float a[16];
#pragma unroll
    for (int k = 0; k < 16; ++k) a[k] = 0.f;
    for (int e = lane; e < DDIM; e += 64) {
        float vv[4];
        vv[0] = xr[e];
        vv[1] = xr[DDIM + e];
        vv[2] = xr[2 * DDIM + e];
        vv[3] = xr[3 * DDIM + e];
#pragma unroll
        for (int i = 0; i < 4; ++i)
#pragma unroll
            for (int j = 0; j < 4; ++j)
                a[i * 4 + j] = fmaf(vv[i], vv[j], a[i * 4 + j]);
    }
#pragma unroll
    for (int k = 0; k < 16; ++k) {
        float t = a[k];
        t += __shfl_xor(t, 32, 64);
        t += __shfl_xor(t, 16, 64);
        t += __shfl_xor(t, 8, 64);
        t += __shfl_xor(t, 4, 64);
        t += __shfl_xor(t, 2, 64);
        t += __shfl_xor(t, 1, 64);
        a[k] = t;
    }
    if (lane == 0) {
        float pos[16];
#pragma unroll
        for (int k = 0; k < 16; ++k) pos[k] = a[k] * INV_T;

        float mx = -pos[0];
#pragma unroll
        for (int k = 1; k < 16; ++k) mx = fmaxf(mx, -pos[k]);
        float se = 0.f;
#pragma unroll
        for (int k = 0; k < 16; ++k) se += __expf(-pos[k] - mx);
        float hard_pos = -T_CONST * (mx + __logf(se));

        float lse_row[4];
#pragma unroll
        for (int i = 0; i < 4; ++i) {
            float m2 = -pos[i * 4];
#pragma unroll
            for (int j = 1; j < 4; ++j) m2 = fmaxf(m2, -pos[i * 4 + j]);
            float s2 = 0.f;
#pragma unroll
            for (int j = 0; j < 4; ++j) s2 += __expf(-pos[i * 4 + j] - m2);
            lse_row[i] = m2 + __logf(s2);
        }
        float m3 = -lse_row[0];
#pragma unroll
        for (int i = 1; i < 4; ++i) m3 = fmaxf(m3, -lse_row[i]);
        float s3 = 0.f;
#pragma unroll
        for (int i = 0; i < 4; ++i) s3 += __expf(-lse_row[i] - m3);
        float least_pos = T_CONST * (m3 + __logf(s3));

        float alpha = (hard_pos >= 0.f)
                          ? (2.f * least_pos * hard_pos) / (hard_pos + least_pos)
                          : 0.f;
        margin[g] = alpha * hard_pos + (1.f - alpha) * least_pos;
    }
}

// Kernel B: one wave per WG, TPW=4 consecutive upper-tri 64x64 tiles.
// A-fragments (full K=256, 64 VGPRs) persist across tiles, reloaded only when
// the tile row ti changes. Direct global fragment loads (R4/R5/R6-verified
// per-lane pattern). acc C/D layout: col = ni*16 + l16,
// row = mi*16 + quad*4 + reg  -> reg spans exactly ONE group of 4 rows.
__global__ __launch_bounds__(64, 2) void gemm_exp_grpsum(const unsigned char* __restrict__ xq,
                                                         float* __restrict__ grpsum) {
    // decode first tile (ti, tj), ti <= tj: off(ti) = ti*(257-ti)/2
    const int idx0 = blockIdx.x * TPW;
    int ti = (int)((257.0f - sqrtf(66049.0f - 8.0f * (float)idx0)) * 0.5f);
    while (ti * (257 - ti) / 2 > idx0) --ti;
    while ((ti + 1) * (256 - ti) / 2 <= idx0) ++ti;
    int tj = ti + (idx0 - ti * (257 - ti) / 2);

    const int lane = threadIdx.x;
    const int quad = lane >> 4;
    const int l16 = lane & 15;

    i32x8_t aF[2][4];   // [ks][mi], register-resident across tiles
    int curTi = -1;

    for (int t = 0; t < TPW; ++t) {
        const int row0 = ti * 64;
        const int col0 = tj * 64;
        const bool diag = (ti == tj);

        if (ti != curTi) {   // wave-uniform; true once for most waves
            curTi = ti;
#pragma unroll
            for (int ks = 0; ks < 2; ++ks)
#pragma unroll
                for (int mi = 0; mi < 4; ++mi) {
                    const unsigned char* pa =
                        xq + ((size_t)(row0 + mi * 16 + l16) << 8) + ks * 128 + quad * 32;
                    i32x4_t lo = *(const i32x4_t*)pa;
                    i32x4_t hi = *(const i32x4_t*)(pa + 16);
                    aF[ks][mi] = __builtin_shufflevector(lo, hi, 0, 1, 2, 3, 4, 5, 6, 7);
                }
        }

        f32x4_t acc[4][4];
#pragma unroll
        for (int i = 0; i < 4; ++i)
#pragma unroll
            for (int j = 0; j < 4; ++j)
                acc[i][j] = (f32x4_t){0.f, 0.f, 0.f, 0.f};

#pragma unroll
        for (int ks = 0; ks < 2; ++ks) {
            i32x8_t bF[4];
#pragma unroll
            for (int ni = 0; ni < 4; ++ni) {
                const unsigned char* pb =
                    xq + ((size_t)(col0 + ni * 16 + l16) << 8) + ks * 128 + quad * 32;
                i32x4_t lo = *(const i32x4_t*)pb;
                i32x4_t hi = *(const i32x4_t*)(pb + 16);
                bF[ni] = __builtin_shufflevector(lo, hi, 0, 1, 2, 3, 4, 5, 6, 7);
            }
#pragma unroll
            for (int mi = 0; mi < 4; ++mi)
#pragma unroll
                for (int ni = 0; ni < 4; ++ni)
                    acc[mi][ni] = __builtin_amdgcn_mfma_scale_f32_16x16x128_f8f6f4(
                        aF[ks][mi], bF[ni], acc[mi][ni],
                        0, 0,                       // fp8 e4m3 A and B
                        0, (int)SCALE_QTR,          // scale A = 2^-4
                        0, (int)SCALE_QTR);         // scale B = 2^-4
        }

        // ---- epilogue: exp + group-granularity sums (verified R6) ----
        const int rg0 = row0 >> 2;
        const int cg0 = col0 >> 2;
        float rowg[4] = {0.f, 0.f, 0.f, 0.f};   // per mi
        float colp[4] = {0.f, 0.f, 0.f, 0.f};   // per ni (per-lane col partial)

        if (!diag) {
#pragma unroll
            for (int mi = 0; mi < 4; ++mi)
#pragma unroll
                for (int reg = 0; reg < 4; ++reg)
#pragma unroll
                    for (int ni = 0; ni < 4; ++ni) {
                        float e = exp2f(acc[mi][ni][reg] * EXP2_SCALE);
                        rowg[mi] += e;
                        colp[ni] += e;
                    }
        } else {
#pragma unroll
            for (int mi = 0; mi < 4; ++mi) {
                const int rgrp = mi * 4 + quad;
#pragma unroll
                for (int reg = 0; reg < 4; ++reg)
#pragma unroll
                    for (int ni = 0; ni < 4; ++ni) {
                        const int cgrp = ni * 4 + (l16 >> 2);
                        float e = (cgrp == rgrp) ? 0.f
                                                 : exp2f(acc[mi][ni][reg] * EXP2_SCALE);
                        rowg[mi] += e;
                    }
            }
        }

#pragma unroll
        for (int mi = 0; mi < 4; ++mi) {
            float v = rowg[mi];
            v += __shfl_xor(v, 1, 64);
            v += __shfl_xor(v, 2, 64);
            v += __shfl_xor(v, 4, 64);
            v += __shfl_xor(v, 8, 64);
            if (l16 == 0) atomicAdd(&grpsum[rg0 + mi * 4 + quad], v);
        }
        if (!diag) {
#pragma unroll
            for (int ni = 0; ni < 4; ++ni) {
                float v = colp[ni];
                v += __shfl_xor(v, 16, 64);
                v += __shfl_xor(v, 32, 64);
                v += __shfl_xor(v, 1, 64);
                v += __shfl_xor(v, 2, 64);
                if (quad == 0 && (l16 & 3) == 0)
                    atomicAdd(&grpsum[cg0 + ni * 4 + (l16 >> 2)], v);
            }
        }

        // advance to next upper-tri tile
        ++tj;
        if (tj == NTB) { ++ti; tj = ti; }
    }
}

// Kernel C: neg[g] = T*log(grpsum[g]); loss = mean softplus((neg-margin)/T).
__global__ __launch_bounds__(256) void finalize_kernel(const float* __restrict__ grpsum,
                                                       const float* __restrict__ margin,
                                                       float* __restrict__ out) {
    const int tid = threadIdx.x;
    float local = 0.f;
    for (int g = tid; g < NGRP; g += 256) {
        float z = __logf(grpsum[g]) - margin[g] * INV_T;   // (neg - margin)/T
        float sp = (z > 30.f) ? z : log1pf(__expf(z));
        local += sp;
    }
    local += __shfl_xor(local, 1, 64);
    local += __shfl_xor(local, 2, 64);
    local += __shfl_xor(local, 4, 64);
    local += __shfl_xor(local, 8, 64);
    local += __shfl_xor(local, 16, 64);
    local += __shfl_xor(local, 32, 64);
    __shared__ float wsum[4];
    if ((tid & 63) == 0) wsum[tid >> 6] = local;
    __syncthreads();
    if (tid == 0) out[0] = (wsum[0] + wsum[1] + wsum[2] + wsum[3]) * (1.f / (float)NGRP);
}

extern "C" void kernel_launch(void* const* d_in, const int* in_sizes, int n_in,
                              void* d_out, int out_size, void* d_ws, size_t ws_size,
                              hipStream_t stream) {
    const float* x = (const float*)d_in[0];
    float* out = (float*)d_out;

    unsigned int* xq = (unsigned int*)d_ws;                                  // 2 MiB fp8 X*16
    float* grpsum = (float*)((char*)d_ws + (size_t)NROWS * DDIM);            // 8 KiB
    float* margin = grpsum + NGRP;                                           // 8 KiB

    prep_kernel<<<1024, 256, 0, stream>>>(x, xq, grpsum, margin);
    gemm_exp_grpsum<<<NWG, 64, 0, stream>>>((const unsigned char*)xq, grpsum);
    finalize_kernel<<<1, 256, 0, stream>>>(grpsum, margin, out);
}

// Round 8
// 109.879 us; speedup vs baseline: 1.1781x; 1.0615x over previous
//
#include <hip/hip_runtime.h>
#include <math.h>

// SP_loss: s = X X^T / T (N=8192, D=256, T=0.04, groups of 4).
// loss = mean_g softplus((neg[g] - margin[g]) / T)
//   neg[g]    = T * log sum_{i in g, j not in g} exp(s[i,j])
//               -> MX-fp8 (e4m3, K=128 scaled MFMA) symmetric GEMM over
//                  upper-tri 64x64 tiles, 1 wave/WG, TPW=4 tiles/wave,
//                  no LDS/barriers/fences.
//   margin[g] = exact fp32 4x4 group Gram block (hard_pos / least_pos / alpha)
//
// R8 changes (VALU diet + latency overlap; kernel is issue-bound at the
// observed effective clock):
//  - X quantized as fp8(x * 6.005612) where 6.005612^2 = 25*log2(e):
//    MFMA (unity scales) yields acc = s*log2(e) -> exp2f(acc), NO per-elem mul.
//  - per-(mi,ni) subtotal shared between row and col partials (80 adds vs 128).
//  - per-lane fragment offsets hoisted out of the tile loop (SALU base + fixed
//    VGPR offset per load).
//  - next tile's B-fragments loaded into the same registers BEFORE the
//    epilogue -> load latency hidden under ~700 cyc of exp/reduce work.

#define NROWS 8192
#define DDIM  256
#define NGRP  2048
#define NTB   128                       // 8192 / 64 tiles per dim
#define NTILES (NTB * (NTB + 1) / 2)    // 8256
#define TPW   4                         // tiles per wave
#define NWG   (NTILES / TPW)            // 2064
#define T_CONST 0.04f
#define INV_T   25.0f
#define QSCALE  6.005612043932249f      // sqrt(25 * log2(e))
#define SCALE_ONE 0x7F7F7F7Fu           // E8M0 127 = 2^0 in every byte

typedef __attribute__((ext_vector_type(8))) int   i32x8_t;
typedef __attribute__((ext_vector_type(4))) int   i32x4_t;
typedef __attribute__((ext_vector_type(4))) float f32x4_t;

__device__ __forceinline__ i32x8_t ldfrag(const unsigned char* base, int off) {
    i32x4_t lo = *(const i32x4_t*)(base + off);
    i32x4_t hi = *(const i32x4_t*)(base + off + 16);
    return __builtin_shufflevector(lo, hi, 0, 1, 2, 3, 4, 5, 6, 7);
}

// Kernel A (fused prep): blocks 0..511 convert fp32 -> fp8 e4m3 (x*QSCALE, RNE,
// x4 per thread) + zero grpsum; blocks 512..1023 compute margin[g]
// (4 groups/block, 1 wave each).
__global__ __launch_bounds__(256) void prep_kernel(const float* __restrict__ x,
                                                   unsigned int* __restrict__ xq,
                                                   float* __restrict__ grpsum,
                                                   float* __restrict__ margin) {
    const int b = blockIdx.x;
    if (b < 512) {
#pragma unroll
        for (int it = 0; it < 4; ++it) {
            int gid = it * 131072 + b * 256 + threadIdx.x;
            float4 v = *(const float4*)(x + (size_t)gid * 4);
            int pk = __builtin_amdgcn_cvt_pk_fp8_f32(v.x * QSCALE, v.y * QSCALE, 0, false);
            pk = __builtin_amdgcn_cvt_pk_fp8_f32(v.z * QSCALE, v.w * QSCALE, pk, true);
            xq[gid] = (unsigned int)pk;
            if (it == 0 && gid < NGRP) grpsum[gid] = 0.f;
        }
        return;
    }
    const int g = (b - 512) * 4 + (threadIdx.x >> 6);
    const int lane = threadIdx.x & 63;
    const float* xr = x + (size_t)g * 4 * DDIM;
    float a[16];
#pragma unroll
    for (int k = 0; k < 16; ++k) a[k] = 0.f;
    for (int e = lane; e < DDIM; e += 64) {
        float vv[4];
        vv[0] = xr[e];
        vv[1] = xr[DDIM + e];
        vv[2] = xr[2 * DDIM + e];
        vv[3] = xr[3 * DDIM + e];
#pragma unroll
        for (int i = 0; i < 4; ++i)
#pragma unroll
            for (int j = 0; j < 4; ++j)
                a[i * 4 + j] = fmaf(vv[i], vv[j], a[i * 4 + j]);
    }
#pragma unroll
    for (int k = 0; k < 16; ++k) {
        float t = a[k];
        t += __shfl_xor(t, 32, 64);
        t += __shfl_xor(t, 16, 64);
        t += __shfl_xor(t, 8, 64);
        t += __shfl_xor(t, 4, 64);
        t += __shfl_xor(t, 2, 64);
        t += __shfl_xor(t, 1, 64);
        a[k] = t;
    }
    if (lane == 0) {
        float pos[16];
#pragma unroll
        for (int k = 0; k < 16; ++k) pos[k] = a[k] * INV_T;

        float mx = -pos[0];
#pragma unroll
        for (int k = 1; k < 16; ++k) mx = fmaxf(mx, -pos[k]);
        float se = 0.f;
#pragma unroll
        for (int k = 0; k < 16; ++k) se += __expf(-pos[k] - mx);
        float hard_pos = -T_CONST * (mx + __logf(se));

        float lse_row[4];
#pragma unroll
        for (int i = 0; i < 4; ++i) {
            float m2 = -pos[i * 4];
#pragma unroll
            for (int j = 1; j < 4; ++j) m2 = fmaxf(m2, -pos[i * 4 + j]);
            float s2 = 0.f;
#pragma unroll
            for (int j = 0; j < 4; ++j) s2 += __expf(-pos[i * 4 + j] - m2);
            lse_row[i] = m2 + __logf(s2);
        }
        float m3 = -lse_row[0];
#pragma unroll
        for (int i = 1; i < 4; ++i) m3 = fmaxf(m3, -lse_row[i]);
        float s3 = 0.f;
#pragma unroll
        for (int i = 0; i < 4; ++i) s3 += __expf(-lse_row[i] - m3);
        float least_pos = T_CONST * (m3 + __logf(s3));

        float alpha = (hard_pos >= 0.f)
                          ? (2.f * least_pos * hard_pos) / (hard_pos + least_pos)
                          : 0.f;
        margin[g] = alpha * hard_pos + (1.f - alpha) * least_pos;
    }
}

// Kernel B: one wave per WG, TPW=4 consecutive upper-tri 64x64 tiles.
// acc C/D layout (verified R4-R7): col = ni*16 + l16, row = mi*16 + quad*4 + reg
// -> reg spans exactly one group of 4 rows.
__global__ __launch_bounds__(64, 2) void gemm_exp_grpsum(const unsigned char* __restrict__ xq,
                                                         float* __restrict__ grpsum) {
    // decode first tile (ti, tj), ti <= tj: off(ti) = ti*(257-ti)/2
    const int idx0 = blockIdx.x * TPW;
    int ti = (int)((257.0f - sqrtf(66049.0f - 8.0f * (float)idx0)) * 0.5f);
    while (ti * (257 - ti) / 2 > idx0) --ti;
    while ((ti + 1) * (256 - ti) / 2 <= idx0) ++ti;
    int tj = ti + (idx0 - ti * (257 - ti) / 2);

    const int lane = threadIdx.x;
    const int quad = lane >> 4;
    const int l16 = lane & 15;

    // per-lane fragment byte offsets, fixed for the whole wave:
    // voff[ks*4+i] = ((i*16 + l16) << 8) + ks*128 + quad*32
    int voff[8];
#pragma unroll
    for (int z = 0; z < 8; ++z)
        voff[z] = (((z & 3) * 16 + l16) << 8) + (z >> 2) * 128 + quad * 32;

    i32x8_t aF[2][4];   // A fragments, full K, persist across tiles
    int curTi = -1;

    // prologue: B fragments (both ks) for the first tile
    i32x8_t bF[2][4];
    {
        const unsigned char* bb = xq + ((size_t)tj << 14);
#pragma unroll
        for (int z = 0; z < 8; ++z) bF[z >> 2][z & 3] = ldfrag(bb, voff[z]);
    }

#pragma unroll
    for (int t = 0; t < TPW; ++t) {
        const bool diag = (ti == tj);
        const int rg0 = ti * 16;
        const int cg0 = tj * 16;

        if (ti != curTi) {   // wave-uniform, true for ~1 tile per wave
            curTi = ti;
            const unsigned char* ab = xq + ((size_t)ti << 14);
#pragma unroll
            for (int z = 0; z < 8; ++z) aF[z >> 2][z & 3] = ldfrag(ab, voff[z]);
        }

        f32x4_t acc[4][4];
#pragma unroll
        for (int i = 0; i < 4; ++i)
#pragma unroll
            for (int j = 0; j < 4; ++j)
                acc[i][j] = (f32x4_t){0.f, 0.f, 0.f, 0.f};

#pragma unroll
        for (int ks = 0; ks < 2; ++ks)
#pragma unroll
            for (int mi = 0; mi < 4; ++mi)
#pragma unroll
                for (int ni = 0; ni < 4; ++ni)
                    acc[mi][ni] = __builtin_amdgcn_mfma_scale_f32_16x16x128_f8f6f4(
                        aF[ks][mi], bF[ks][ni], acc[mi][ni],
                        0, 0,                       // fp8 e4m3 A and B
                        0, (int)SCALE_ONE,          // scale A = 1
                        0, (int)SCALE_ONE);         // scale B = 1

        // advance to next tile and prefetch its B into the SAME registers,
        // BEFORE the epilogue: load latency hides under exp/reduce work.
        const int ptj = tj;  (void)ptj;
        ++tj;
        if (tj == NTB) { ++ti; tj = ti; }
        if (t + 1 < TPW) {
            const unsigned char* bb = xq + ((size_t)tj << 14);
#pragma unroll
            for (int z = 0; z < 8; ++z) bF[z >> 2][z & 3] = ldfrag(bb, voff[z]);
        }

        // ---- epilogue: acc already = s*log2(e); exp2 + group sums ----
        float rowg[4] = {0.f, 0.f, 0.f, 0.f};
        float colp[4] = {0.f, 0.f, 0.f, 0.f};

        if (!diag) {
#pragma unroll
            for (int mi = 0; mi < 4; ++mi)
#pragma unroll
                for (int ni = 0; ni < 4; ++ni) {
                    float s4 = exp2f(acc[mi][ni][0]) + exp2f(acc[mi][ni][1])
                             + exp2f(acc[mi][ni][2]) + exp2f(acc[mi][ni][3]);
                    rowg[mi] += s4;
                    colp[ni] += s4;
                }
        } else {
#pragma unroll
            for (int mi = 0; mi < 4; ++mi) {
                const int rgrp = mi * 4 + quad;
#pragma unroll
                for (int ni = 0; ni < 4; ++ni) {
                    const int cgrp = ni * 4 + (l16 >> 2);
                    if (cgrp != rgrp) {
                        float s4 = exp2f(acc[mi][ni][0]) + exp2f(acc[mi][ni][1])
                                 + exp2f(acc[mi][ni][2]) + exp2f(acc[mi][ni][3]);
                        rowg[mi] += s4;   // rows only on diag (full block present)
                    }
                }
            }
        }

        // row groups: reduce over the 16 col-lanes of each quad-phase
#pragma unroll
        for (int mi = 0; mi < 4; ++mi) {
            float v = rowg[mi];
            v += __shfl_xor(v, 1, 64);
            v += __shfl_xor(v, 2, 64);
            v += __shfl_xor(v, 4, 64);
            v += __shfl_xor(v, 8, 64);
            if (l16 == 0) atomicAdd(&grpsum[rg0 + mi * 4 + quad], v);
        }
        if (!diag) {
            // col groups: reduce over quad (xor 16,32) and 4-lane cluster (xor 1,2)
#pragma unroll
            for (int ni = 0; ni < 4; ++ni) {
                float v = colp[ni];
                v += __shfl_xor(v, 16, 64);
                v += __shfl_xor(v, 32, 64);
                v += __shfl_xor(v, 1, 64);
                v += __shfl_xor(v, 2, 64);
                if (quad == 0 && (l16 & 3) == 0)
                    atomicAdd(&grpsum[cg0 + ni * 4 + (l16 >> 2)], v);
            }
        }
    }
}

// Kernel C: neg[g] = T*log(grpsum[g]); loss = mean softplus((neg-margin)/T).
__global__ __launch_bounds__(256) void finalize_kernel(const float* __restrict__ grpsum,
                                                       const float* __restrict__ margin,
                                                       float* __restrict__ out) {
    const int tid = threadIdx.x;
    float local = 0.f;
    for (int g = tid; g < NGRP; g += 256) {
        float z = __logf(grpsum[g]) - margin[g] * INV_T;   // (neg - margin)/T
        float sp = (z > 30.f) ? z : log1pf(__expf(z));
        local += sp;
    }
    local += __shfl_xor(local, 1, 64);
    local += __shfl_xor(local, 2, 64);
    local += __shfl_xor(local, 4, 64);
    local += __shfl_xor(local, 8, 64);
    local += __shfl_xor(local, 16, 64);
    local += __shfl_xor(local, 32, 64);
    __shared__ float wsum[4];
    if ((tid & 63) == 0) wsum[tid >> 6] = local;
    __syncthreads();
    if (tid == 0) out[0] = (wsum[0] + wsum[1] + wsum[2] + wsum[3]) * (1.f / (float)NGRP);
}

extern "C" void kernel_launch(void* const* d_in, const int* in_sizes, int n_in,
                              void* d_out, int out_size, void* d_ws, size_t ws_size,
                              hipStream_t stream) {
    const float* x = (const float*)d_in[0];
    float* out = (float*)d_out;

    unsigned int* xq = (unsigned int*)d_ws;                                  // 2 MiB fp8 X*c
    float* grpsum = (float*)((char*)d_ws + (size_t)NROWS * DDIM);            // 8 KiB
    float* margin = grpsum + NGRP;                                           // 8 KiB

    prep_kernel<<<1024, 256, 0, stream>>>(x, xq, grpsum, margin);
    gemm_exp_grpsum<<<NWG, 64, 0, stream>>>((const unsigned char*)xq, grpsum);
    finalize_kernel<<<1, 256, 0, stream>>>(grpsum, margin, out);
}